// Round 12
// baseline (86.549 us; speedup 1.0000x reference)
//
#include <hip/hip_runtime.h>
#include <hip/hip_bf16.h>
#include <math.h>

// Problem constants (fixed by setup_inputs)
#define B_ 4
#define L_ 8192
#define M_ 4096
#define D_ 1024
#define CHUNK_ 32
#define NCC_ 128        // M_/CHUNK_
#define EPS_ 1e-4f
#define GRID_AB (NCC_ * B_)   // 512 blocks in k_scanAB
#define WORKERS_ 64           // last 64 ticket-holders run the chunk chain
#define AGENT __HIP_MEMORY_SCOPE_AGENT

// clang native vector type for nontemporal builtins (same layout as float4)
typedef float f32x4 __attribute__((ext_vector_type(4)));

// Round-to-nearest-even f32 -> bf16 -> f32 (values are finite here)
__device__ __forceinline__ float bf16rf(float x) {
  unsigned u = __float_as_uint(x);
  u += 0x7FFFu + ((u >> 16) & 1u);
  u &= 0xFFFF0000u;
  return __uint_as_float(u);
}

// boundary_mask may arrive as bool8 (fmt 0), int32 (fmt 1), or float32 (fmt 2)
__device__ __forceinline__ bool mask_at(const void* mb, int fmt, int i) {
  if (fmt == 0) return ((const unsigned char*)mb)[i] != 0;
  if (fmt == 1) return ((const int*)mb)[i] != 0;
  return ((const float*)mb)[i] != 0.0f;
}

// Compute per-chunk scalars into LDS: s_scal[tid] = (a, c=dt*p, 1/dt, 0)
// for tid < CHUNK_. Deterministic -> identical values in scanAB and scanC.
__device__ __forceinline__ void chunk_scal(const float* __restrict__ p_sorted,
                                           int b, int c, int tid,
                                           float4* s_scal) {
  if (tid < CHUNK_) {
    float p = p_sorted[b * M_ + c * CHUNK_ + tid];
    p = fminf(fmaxf(p, EPS_), 1.0f - EPS_);
    float dtf = bf16rf(logf(1.0f / (1.0f - p)));
    s_scal[tid] = make_float4(expf(-dtf), dtf * p, 1.0f / dtf, 0.0f);
  }
}

// prep: one 1024-thread block per batch; sort-only (R11-proven).
__global__ void __launch_bounds__(1024)
k_prep(const float* __restrict__ bprob,
       const void* __restrict__ bmask,
       float* __restrict__ p_sorted,
       int* __restrict__ rowstart) {
  const int b = blockIdx.x;
  const int tid = threadIdx.x;  // 0..1023
  const int lane = tid & 63, wid = tid >> 6;
  __shared__ int s_flags[2];
  __shared__ int s_wsum[17];

  if (tid < 2) s_flags[tid] = 0;
  __syncthreads();
  {
    const unsigned* mw = (const unsigned*)bmask;
    unsigned f0 = 0, f1 = 0;
    for (int i = tid; i < 8192; i += 1024) {
      unsigned v = mw[i];
      f0 |= v & 0xFFu;    // byte0: nonzero for u8 and i32, zero for f32
      f1 |= v & 0xFF00u;  // byte1: nonzero only for u8 (45% density)
    }
    if (f1) s_flags[0] = 1;
    if (f0) s_flags[1] = 1;
  }
  __syncthreads();
  const int fmt = s_flags[0] ? 0 : (s_flags[1] ? 1 : 2);

  const int base_l = tid * (L_ / 1024);
  bool mloc[L_ / 1024];
  int cnt = 0;
#pragma unroll
  for (int j = 0; j < L_ / 1024; ++j) {
    mloc[j] = mask_at(bmask, fmt, b * L_ + base_l + j);
    cnt += mloc[j] ? 1 : 0;
  }
  int incl = cnt;
#pragma unroll
  for (int off = 1; off < 64; off <<= 1) {
    int t = __shfl_up(incl, off);
    if (lane >= off) incl += t;
  }
  if (lane == 63) s_wsum[wid] = incl;
  __syncthreads();
  if (tid == 0) {
    int acc = 0;
#pragma unroll
    for (int w = 0; w < 16; ++w) { int t = s_wsum[w]; s_wsum[w] = acc; acc += t; }
    s_wsum[16] = acc;
  }
  for (int r = tid; r <= M_; r += 1024) rowstart[b * (M_ + 1) + r] = L_;
  __syncthreads();
  const int excl = s_wsum[wid] + incl - cnt;
  const int nb = s_wsum[16];

  int run = excl;
#pragma unroll
  for (int j = 0; j < L_ / 1024; ++j) {
    int l = base_l + j;
    bool mb = mloc[j];
    int pos = mb ? run : (nb + (l - run));
    run += mb ? 1 : 0;
    if (pos < M_) {
      p_sorted[b * M_ + pos] = bprob[((size_t)(b * L_ + l)) * 2 + 1];
      if (mb) rowstart[b * (M_ + 1) + pos] = l;
    }
  }
}

// Pass A+B fused: local chunk scan publishes partials agent-scope, then a
// finish-ticket. The last WORKERS_ ticket-holders spin on the one counter
// until all blocks have ticketed (=> all partials visible), then run the
// batched chunk-chain scan in place. Non-workers never wait -> counter
// always reaches GRID_AB -> deadlock-free at any occupancy.
__global__ void __launch_bounds__(256)
k_scanAB(const float* __restrict__ hidden,
         const float* __restrict__ p_sorted,
         const int* __restrict__ rowstart,
         float* __restrict__ carry,      // [B][NCC][D]
         float* __restrict__ Achunk,     // [B][NCC]
         unsigned* __restrict__ counter) {
  const int c = blockIdx.x, b = blockIdx.y;
  const int tid = threadIdx.x;
  __shared__ float4 s_scal[CHUNK_];
  __shared__ unsigned s_ticket;
  const bool active = (rowstart[b * (M_ + 1) + c * CHUNK_] < L_);

  if (active) {
    chunk_scal(p_sorted, b, c, tid, s_scal);
    __syncthreads();
    if (tid == 0) {
      float cp = 1.0f;
#pragma unroll
      for (int m = 0; m < CHUNK_; ++m) cp *= s_scal[m].x;
      __hip_atomic_store(&Achunk[b * NCC_ + c], cp, __ATOMIC_RELAXED, AGENT);
    }
    const int d4 = tid * 4;
    const float* __restrict__ hp =
        hidden + ((size_t)(b * M_ + c * CHUNK_)) * D_ + d4;
    float hx = 0.f, hy = 0.f, hz = 0.f, hw = 0.f;
#pragma unroll
    for (int m = 0; m < CHUNK_; ++m) {
      const float4 s = s_scal[m];                 // a, c=dt*p, 1/dt
      const float4 x = *(const float4*)(hp + (size_t)m * D_);
      hx = fmaf(s.x, hx, s.y * bf16rf(x.x * s.z));
      hy = fmaf(s.x, hy, s.y * bf16rf(x.y * s.z));
      hz = fmaf(s.x, hz, s.y * bf16rf(x.z * s.z));
      hw = fmaf(s.x, hw, s.y * bf16rf(x.w * s.z));
    }
    float* cp_ = carry + ((size_t)(b * NCC_ + c)) * D_ + d4;
    __hip_atomic_store(cp_ + 0, hx, __ATOMIC_RELAXED, AGENT);
    __hip_atomic_store(cp_ + 1, hy, __ATOMIC_RELAXED, AGENT);
    __hip_atomic_store(cp_ + 2, hz, __ATOMIC_RELAXED, AGENT);
    __hip_atomic_store(cp_ + 3, hw, __ATOMIC_RELAXED, AGENT);
  }
  __syncthreads();  // drains all waves' stores (vmcnt 0 before barrier)
  if (tid == 0)
    s_ticket = __hip_atomic_fetch_add(counter, 1u, __ATOMIC_ACQ_REL, AGENT);
  __syncthreads();
  const unsigned ticket = s_ticket;
  if (ticket < (unsigned)(GRID_AB - WORKERS_)) return;

  // Worker: wait until every block has ticketed (their partials are visible).
  if (tid == 0) {
    while (__hip_atomic_load(counter, __ATOMIC_ACQUIRE, AGENT) <
           (unsigned)GRID_AB)
      __builtin_amdgcn_s_sleep(2);
  }
  __syncthreads();
  if (tid < 64) {
    const int chain = (int)(ticket - (GRID_AB - WORKERS_)) * 64 + tid; // 0..4095
    const int bb = chain >> 10, dd = chain & 1023;
    float S = 0.0f;
    for (int g = 0; g < NCC_ / 16; ++g) {
      float v[16], A[16];
#pragma unroll
      for (int j = 0; j < 16; ++j)
        v[j] = __hip_atomic_load(
            &carry[((size_t)(bb * NCC_ + g * 16 + j)) * D_ + dd],
            __ATOMIC_RELAXED, AGENT);
#pragma unroll
      for (int j = 0; j < 16; ++j)
        A[j] = __hip_atomic_load(&Achunk[bb * NCC_ + g * 16 + j],
                                 __ATOMIC_RELAXED, AGENT);
#pragma unroll
      for (int j = 0; j < 16; ++j) { S = fmaf(A[j], S, v[j]); v[j] = S; }
#pragma unroll
      for (int j = 0; j < 16; ++j)
        __hip_atomic_store(
            &carry[((size_t)(bb * NCC_ + g * 16 + j)) * D_ + dd], v[j],
            __ATOMIC_RELAXED, AGENT);
    }
  }
}

// Pass C: inactive-exit first, carry-in load issued early, local rescan of
// hidden with true carry-in, fused scatter with nontemporal stores.
__global__ void __launch_bounds__(256)
k_scanC(const float* __restrict__ hidden,
        const float* __restrict__ p_sorted,
        const int* __restrict__ rowstart,
        const float* __restrict__ carry,
        float* __restrict__ out) {
  const int c = blockIdx.x, b = blockIdx.y;
  const int tid = threadIdx.x;
  if (rowstart[b * (M_ + 1) + c * CHUNK_] >= L_) return;  // inactive chunk
  const int d4 = tid * 4;
  __shared__ float4 s_scal[CHUNK_];
  __shared__ int    s_rs[CHUNK_ + 1];

  // issue carry-in load first so it overlaps the LDS/scal phase
  float hx = 0.f, hy = 0.f, hz = 0.f, hw = 0.f;
  if (c > 0) {
    const float4 ci =
        *(const float4*)(carry + ((size_t)(b * NCC_ + c - 1)) * D_ + d4);
    hx = ci.x; hy = ci.y; hz = ci.z; hw = ci.w;
  }
  chunk_scal(p_sorted, b, c, tid, s_scal);
  if (tid <= CHUNK_) s_rs[tid] = rowstart[b * (M_ + 1) + c * CHUNK_ + tid];
  __syncthreads();

  const float* __restrict__ hp =
      hidden + ((size_t)(b * M_ + c * CHUNK_)) * D_ + d4;
#pragma unroll
  for (int m = 0; m < CHUNK_; ++m) {
    const float4 s = s_scal[m];
    const float4 x = *(const float4*)(hp + (size_t)m * D_);
    hx = fmaf(s.x, hx, s.y * bf16rf(x.x * s.z));
    hy = fmaf(s.x, hy, s.y * bf16rf(x.y * s.z));
    hz = fmaf(s.x, hz, s.y * bf16rf(x.z * s.z));
    hw = fmaf(s.x, hw, s.y * bf16rf(x.w * s.z));
    const int r0 = s_rs[m], r1 = s_rs[m + 1];
    if (r1 > r0) {
      f32x4 o;
      o.x = bf16rf(hx); o.y = bf16rf(hy);
      o.z = bf16rf(hz); o.w = bf16rf(hw);
      for (int l = r0; l < r1; ++l)
        __builtin_nontemporal_store(
            o, (f32x4*)(out + ((size_t)(b * L_ + l)) * D_ + d4));
    }
  }
}

extern "C" void kernel_launch(void* const* d_in, const int* in_sizes, int n_in,
                              void* d_out, int out_size, void* d_ws, size_t ws_size,
                              hipStream_t stream) {
  const float* hidden = (const float*)d_in[0];
  const float* bprob  = (const float*)d_in[1];
  const void*  bmask  = d_in[2];
  float* out = (float*)d_out;

  float*    p_sorted = (float*)d_ws;                          // B*M
  float*    carry    = p_sorted + B_ * M_;                    // B*NCC*D
  float*    Achunk   = carry + (size_t)B_ * NCC_ * D_;        // B*NCC
  int*      rowstart = (int*)(Achunk + B_ * NCC_);            // B*(M+1)
  unsigned* counter  = (unsigned*)(rowstart + B_ * (M_ + 1)); // 1

  hipMemsetAsync((void*)counter, 0, sizeof(unsigned), stream);
  k_prep<<<dim3(B_), dim3(1024), 0, stream>>>(bprob, bmask, p_sorted, rowstart);
  k_scanAB<<<dim3(NCC_, B_), dim3(256), 0, stream>>>(hidden, p_sorted, rowstart,
                                                     carry, Achunk, counter);
  k_scanC<<<dim3(NCC_, B_), dim3(256), 0, stream>>>(hidden, p_sorted, rowstart,
                                                    carry, out);
}

// Round 13
// 81.786 us; speedup vs baseline: 1.0582x; 1.0582x over previous
//
#include <hip/hip_runtime.h>
#include <hip/hip_bf16.h>
#include <math.h>

// Problem constants (fixed by setup_inputs)
#define B_ 4
#define L_ 8192
#define M_ 4096
#define D_ 1024
#define CHUNK_ 32
#define NCC_ 128        // M_/CHUNK_
#define EPS_ 1e-4f
#define NWORK_ 16       // worker blocks in k_scanBC (first-dispatched)
#define AGENT __HIP_MEMORY_SCOPE_AGENT

// clang native vector type for nontemporal builtins (same layout as float4)
typedef float f32x4 __attribute__((ext_vector_type(4)));

// Round-to-nearest-even f32 -> bf16 -> f32 (values are finite here)
__device__ __forceinline__ float bf16rf(float x) {
  unsigned u = __float_as_uint(x);
  u += 0x7FFFu + ((u >> 16) & 1u);
  u &= 0xFFFF0000u;
  return __uint_as_float(u);
}

// boundary_mask may arrive as bool8 (fmt 0), int32 (fmt 1), or float32 (fmt 2)
__device__ __forceinline__ bool mask_at(const void* mb, int fmt, int i) {
  if (fmt == 0) return ((const unsigned char*)mb)[i] != 0;
  if (fmt == 1) return ((const int*)mb)[i] != 0;
  return ((const float*)mb)[i] != 0.0f;
}

// Compute per-chunk scalars into LDS: s_scal[tid] = (a, c=dt*p, 1/dt, 0)
// for tid < CHUNK_. Deterministic -> identical values in scanA and scanBC.
__device__ __forceinline__ void chunk_scal(const float* __restrict__ p_sorted,
                                           int b, int c, int tid,
                                           float4* s_scal) {
  if (tid < CHUNK_) {
    float p = p_sorted[b * M_ + c * CHUNK_ + tid];
    p = fminf(fmaxf(p, EPS_), 1.0f - EPS_);
    float dtf = bf16rf(logf(1.0f / (1.0f - p)));
    s_scal[tid] = make_float4(expf(-dtf), dtf * p, 1.0f / dtf, 0.0f);
  }
}

// prep: one 1024-thread block per batch; sort-only (R11-proven). Also
// resets the scanBC counter (kernel-boundary coherence covers visibility).
__global__ void __launch_bounds__(1024)
k_prep(const float* __restrict__ bprob,
       const void* __restrict__ bmask,
       float* __restrict__ p_sorted,
       int* __restrict__ rowstart,
       unsigned* __restrict__ counter) {
  const int b = blockIdx.x;
  const int tid = threadIdx.x;  // 0..1023
  const int lane = tid & 63, wid = tid >> 6;
  __shared__ int s_flags[2];
  __shared__ int s_wsum[17];

  if (b == 0 && tid == 0) *counter = 0u;
  if (tid < 2) s_flags[tid] = 0;
  __syncthreads();
  {
    const unsigned* mw = (const unsigned*)bmask;
    unsigned f0 = 0, f1 = 0;
    for (int i = tid; i < 8192; i += 1024) {
      unsigned v = mw[i];
      f0 |= v & 0xFFu;    // byte0: nonzero for u8 and i32, zero for f32
      f1 |= v & 0xFF00u;  // byte1: nonzero only for u8 (45% density)
    }
    if (f1) s_flags[0] = 1;
    if (f0) s_flags[1] = 1;
  }
  __syncthreads();
  const int fmt = s_flags[0] ? 0 : (s_flags[1] ? 1 : 2);

  const int base_l = tid * (L_ / 1024);
  bool mloc[L_ / 1024];
  int cnt = 0;
#pragma unroll
  for (int j = 0; j < L_ / 1024; ++j) {
    mloc[j] = mask_at(bmask, fmt, b * L_ + base_l + j);
    cnt += mloc[j] ? 1 : 0;
  }
  int incl = cnt;
#pragma unroll
  for (int off = 1; off < 64; off <<= 1) {
    int t = __shfl_up(incl, off);
    if (lane >= off) incl += t;
  }
  if (lane == 63) s_wsum[wid] = incl;
  __syncthreads();
  if (tid == 0) {
    int acc = 0;
#pragma unroll
    for (int w = 0; w < 16; ++w) { int t = s_wsum[w]; s_wsum[w] = acc; acc += t; }
    s_wsum[16] = acc;
  }
  for (int r = tid; r <= M_; r += 1024) rowstart[b * (M_ + 1) + r] = L_;
  __syncthreads();
  const int excl = s_wsum[wid] + incl - cnt;
  const int nb = s_wsum[16];

  int run = excl;
#pragma unroll
  for (int j = 0; j < L_ / 1024; ++j) {
    int l = base_l + j;
    bool mb = mloc[j];
    int pos = mb ? run : (nb + (l - run));
    run += mb ? 1 : 0;
    if (pos < M_) {
      p_sorted[b * M_ + pos] = bprob[((size_t)(b * L_ + l)) * 2 + 1];
      if (mb) rowstart[b * (M_ + 1) + pos] = l;
    }
  }
}

// Pass A: per-(batch,chunk) local scan with zero carry-in; plain float4
// stores for carry (kernel boundary provides coherence). R11-identical.
__global__ void __launch_bounds__(256)
k_scanA(const float* __restrict__ hidden,
        const float* __restrict__ p_sorted,
        const int* __restrict__ rowstart,
        float* __restrict__ carry,     // [B][NCC][D]
        float* __restrict__ Achunk) {  // [B][NCC]
  const int c = blockIdx.x, b = blockIdx.y;
  const int tid = threadIdx.x;
  if (rowstart[b * (M_ + 1) + c * CHUNK_] >= L_) return;  // inactive chunk
  __shared__ float4 s_scal[CHUNK_];
  chunk_scal(p_sorted, b, c, tid, s_scal);
  __syncthreads();
  if (tid == 0) {
    float cp = 1.0f;
#pragma unroll
    for (int m = 0; m < CHUNK_; ++m) cp *= s_scal[m].x;
    Achunk[b * NCC_ + c] = cp;
  }
  const int d4 = tid * 4;
  const float* __restrict__ hp =
      hidden + ((size_t)(b * M_ + c * CHUNK_)) * D_ + d4;
  float hx = 0.f, hy = 0.f, hz = 0.f, hw = 0.f;
#pragma unroll
  for (int m = 0; m < CHUNK_; ++m) {
    const float4 s = s_scal[m];                 // a, c=dt*p, 1/dt
    const float4 x = *(const float4*)(hp + (size_t)m * D_);
    hx = fmaf(s.x, hx, s.y * bf16rf(x.x * s.z));
    hy = fmaf(s.x, hy, s.y * bf16rf(x.y * s.z));
    hz = fmaf(s.x, hz, s.y * bf16rf(x.z * s.z));
    hw = fmaf(s.x, hw, s.y * bf16rf(x.w * s.z));
  }
  *(float4*)(carry + ((size_t)(b * NCC_ + c)) * D_ + d4) =
      make_float4(hx, hy, hz, hw);
}

// Pass B+C fused. Linear grid of 512 blocks: bx -> (b = bx>>7, c = bx&127).
// Blocks 0..15 (first-dispatched, always resident) are ALSO chain workers:
// they run the batched chunk-chain scan (normal loads; agent-relaxed scalar
// stores publish results), then one ACQ_REL ticket each (16 total -- cheap,
// unlike R12's 512). Every block then does its chunk duty: scal/rowstart
// LDS phase (overlaps the chain), relaxed spin on the counter (c>0 only),
// acquire fence, agent-load its 16B carry-in, rescan hidden, NT scatter.
__global__ void __launch_bounds__(256)
k_scanBC(const float* __restrict__ hidden,
         const float* __restrict__ p_sorted,
         const int* __restrict__ rowstart,
         float* __restrict__ carry,      // [B][NCC][D]
         const float* __restrict__ Achunk,
         unsigned* __restrict__ counter,
         float* __restrict__ out) {
  const int bx = blockIdx.x;
  const int c = bx & (NCC_ - 1), b = bx >> 7;
  const int tid = threadIdx.x;

  // ---- Phase W: chain scan on the 16 first-dispatched blocks ----
  if (bx < NWORK_) {
    const int chain = bx * 256 + tid;          // 0..4095 = (bb, dd)
    const int bb = chain >> 10, dd = chain & 1023;
    const float* __restrict__ Ab = Achunk + bb * NCC_;
    float S = 0.0f;
    for (int g = 0; g < NCC_ / 16; ++g) {
      float v[16], A[16];
#pragma unroll
      for (int j = 0; j < 16; ++j)
        v[j] = carry[((size_t)(bb * NCC_ + g * 16 + j)) * D_ + dd];
#pragma unroll
      for (int j = 0; j < 16; ++j) A[j] = Ab[g * 16 + j];
#pragma unroll
      for (int j = 0; j < 16; ++j) { S = fmaf(A[j], S, v[j]); v[j] = S; }
#pragma unroll
      for (int j = 0; j < 16; ++j)
        __hip_atomic_store(
            &carry[((size_t)(bb * NCC_ + g * 16 + j)) * D_ + dd], v[j],
            __ATOMIC_RELAXED, AGENT);
    }
    __syncthreads();
    if (tid == 0)
      __hip_atomic_fetch_add(counter, 1u, __ATOMIC_ACQ_REL, AGENT);
  }

  // ---- Phase C: chunk duty (all 512 blocks) ----
  __shared__ float4 s_scal[CHUNK_];
  __shared__ int    s_rs[CHUNK_ + 1];
  chunk_scal(p_sorted, b, c, tid, s_scal);
  if (tid <= CHUNK_) s_rs[tid] = rowstart[b * (M_ + 1) + c * CHUNK_ + tid];
  __syncthreads();
  if (s_rs[0] >= L_) return;                    // inactive chunk

  const int d4 = tid * 4;
  float hx = 0.f, hy = 0.f, hz = 0.f, hw = 0.f;
  if (c > 0) {
    if (tid == 0) {
      while (__hip_atomic_load(counter, __ATOMIC_RELAXED, AGENT) <
             (unsigned)NWORK_)
        __builtin_amdgcn_s_sleep(2);
    }
    __syncthreads();
    __builtin_amdgcn_fence(__ATOMIC_ACQUIRE, "agent");
    const float* ip = carry + ((size_t)(b * NCC_ + c - 1)) * D_ + d4;
    hx = __hip_atomic_load(ip + 0, __ATOMIC_RELAXED, AGENT);
    hy = __hip_atomic_load(ip + 1, __ATOMIC_RELAXED, AGENT);
    hz = __hip_atomic_load(ip + 2, __ATOMIC_RELAXED, AGENT);
    hw = __hip_atomic_load(ip + 3, __ATOMIC_RELAXED, AGENT);
  }

  const float* __restrict__ hp =
      hidden + ((size_t)(b * M_ + c * CHUNK_)) * D_ + d4;
#pragma unroll
  for (int m = 0; m < CHUNK_; ++m) {
    const float4 s = s_scal[m];
    const float4 x = *(const float4*)(hp + (size_t)m * D_);
    hx = fmaf(s.x, hx, s.y * bf16rf(x.x * s.z));
    hy = fmaf(s.x, hy, s.y * bf16rf(x.y * s.z));
    hz = fmaf(s.x, hz, s.y * bf16rf(x.z * s.z));
    hw = fmaf(s.x, hw, s.y * bf16rf(x.w * s.z));
    const int r0 = s_rs[m], r1 = s_rs[m + 1];
    if (r1 > r0) {
      f32x4 o;
      o.x = bf16rf(hx); o.y = bf16rf(hy);
      o.z = bf16rf(hz); o.w = bf16rf(hw);
      for (int l = r0; l < r1; ++l)
        __builtin_nontemporal_store(
            o, (f32x4*)(out + ((size_t)(b * L_ + l)) * D_ + d4));
    }
  }
}

extern "C" void kernel_launch(void* const* d_in, const int* in_sizes, int n_in,
                              void* d_out, int out_size, void* d_ws, size_t ws_size,
                              hipStream_t stream) {
  const float* hidden = (const float*)d_in[0];
  const float* bprob  = (const float*)d_in[1];
  const void*  bmask  = d_in[2];
  float* out = (float*)d_out;

  float*    p_sorted = (float*)d_ws;                          // B*M
  float*    carry    = p_sorted + B_ * M_;                    // B*NCC*D
  float*    Achunk   = carry + (size_t)B_ * NCC_ * D_;        // B*NCC
  int*      rowstart = (int*)(Achunk + B_ * NCC_);            // B*(M+1)
  unsigned* counter  = (unsigned*)(rowstart + B_ * (M_ + 1)); // 1

  k_prep<<<dim3(B_), dim3(1024), 0, stream>>>(bprob, bmask, p_sorted, rowstart,
                                              counter);
  k_scanA<<<dim3(NCC_, B_), dim3(256), 0, stream>>>(hidden, p_sorted, rowstart,
                                                    carry, Achunk);
  k_scanBC<<<dim3(NCC_ * B_), dim3(256), 0, stream>>>(hidden, p_sorted, rowstart,
                                                      carry, Achunk, counter, out);
}

// Round 14
// 67.020 us; speedup vs baseline: 1.2914x; 1.2203x over previous
//
#include <hip/hip_runtime.h>
#include <hip/hip_bf16.h>
#include <math.h>

// Problem constants (fixed by setup_inputs)
#define B_ 4
#define L_ 8192
#define M_ 4096
#define D_ 1024
#define CHUNK_ 32
#define NCC_ 128        // M_/CHUNK_
#define EPS_ 1e-4f

// clang native vector type for nontemporal builtins (same layout as float4)
typedef float f32x4 __attribute__((ext_vector_type(4)));

// Round-to-nearest-even f32 -> bf16 -> f32 (values are finite here)
__device__ __forceinline__ float bf16rf(float x) {
  unsigned u = __float_as_uint(x);
  u += 0x7FFFu + ((u >> 16) & 1u);
  u &= 0xFFFF0000u;
  return __uint_as_float(u);
}

// boundary_mask may arrive as bool8 (fmt 0), int32 (fmt 1), or float32 (fmt 2)
__device__ __forceinline__ bool mask_at(const void* mb, int fmt, int i) {
  if (fmt == 0) return ((const unsigned char*)mb)[i] != 0;
  if (fmt == 1) return ((const int*)mb)[i] != 0;
  return ((const float*)mb)[i] != 0.0f;
}

// Compute per-chunk scalars into LDS: s_scal[tid] = (a, c=dt*p, 1/dt, 0)
// for tid < CHUNK_. Deterministic -> identical values in scanA and scanC.
__device__ __forceinline__ void chunk_scal(const float* __restrict__ p_sorted,
                                           int b, int c, int tid,
                                           float4* s_scal) {
  if (tid < CHUNK_) {
    float p = p_sorted[b * M_ + c * CHUNK_ + tid];
    p = fminf(fmaxf(p, EPS_), 1.0f - EPS_);
    float dtf = bf16rf(logf(1.0f / (1.0f - p)));
    s_scal[tid] = make_float4(expf(-dtf), dtf * p, 1.0f / dtf, 0.0f);
  }
}

// prep: one 1024-thread block per batch; sort-only. Scatters go to LDS,
// global writes are coalesced (R11's scattered 4B global writes removed).
__global__ void __launch_bounds__(1024)
k_prep(const float* __restrict__ bprob,
       const void* __restrict__ bmask,
       float* __restrict__ p_sorted,
       int* __restrict__ rowstart) {
  const int b = blockIdx.x;
  const int tid = threadIdx.x;  // 0..1023
  const int lane = tid & 63, wid = tid >> 6;
  __shared__ int s_flags[2];
  __shared__ int s_wsum[17];
  __shared__ float s_p[M_];        // 16 KB
  __shared__ int   s_rsl[M_ + 1];  // 16 KB + 4

  if (tid < 2) s_flags[tid] = 0;
  __syncthreads();
  {
    const unsigned* mw = (const unsigned*)bmask;
    unsigned f0 = 0, f1 = 0;
    for (int i = tid; i < 8192; i += 1024) {
      unsigned v = mw[i];
      f0 |= v & 0xFFu;    // byte0: nonzero for u8 and i32, zero for f32
      f1 |= v & 0xFF00u;  // byte1: nonzero only for u8 (45% density)
    }
    if (f1) s_flags[0] = 1;
    if (f0) s_flags[1] = 1;
  }
  __syncthreads();
  const int fmt = s_flags[0] ? 0 : (s_flags[1] ? 1 : 2);

  // 8 contiguous tokens per thread
  const int base_l = tid * (L_ / 1024);
  bool mloc[L_ / 1024];
  int cnt = 0;
#pragma unroll
  for (int j = 0; j < L_ / 1024; ++j) {
    mloc[j] = mask_at(bmask, fmt, b * L_ + base_l + j);
    cnt += mloc[j] ? 1 : 0;
  }
  // wave-level inclusive scan of cnt (wave = 64 on gfx950)
  int incl = cnt;
#pragma unroll
  for (int off = 1; off < 64; off <<= 1) {
    int t = __shfl_up(incl, off);
    if (lane >= off) incl += t;
  }
  if (lane == 63) s_wsum[wid] = incl;
  // default rowstart while the scan settles
  for (int r = tid; r <= M_; r += 1024) s_rsl[r] = L_;
  __syncthreads();
  if (tid == 0) {
    int acc = 0;
#pragma unroll
    for (int w = 0; w < 16; ++w) { int t = s_wsum[w]; s_wsum[w] = acc; acc += t; }
    s_wsum[16] = acc;
  }
  __syncthreads();
  const int excl = s_wsum[wid] + incl - cnt;
  const int nb = s_wsum[16];

  int run = excl;
#pragma unroll
  for (int j = 0; j < L_ / 1024; ++j) {
    int l = base_l + j;
    bool mb = mloc[j];
    int pos = mb ? run : (nb + (l - run));
    run += mb ? 1 : 0;
    if (pos < M_) {
      s_p[pos] = bprob[((size_t)(b * L_ + l)) * 2 + 1];
      if (mb) s_rsl[pos] = l;
    }
  }
  __syncthreads();

  // coalesced write-out
  for (int m = tid; m < M_; m += 1024) p_sorted[b * M_ + m] = s_p[m];
  for (int r = tid; r <= M_; r += 1024) rowstart[b * (M_ + 1) + r] = s_rsl[r];
}

// Pass A: per-(batch,chunk) local scan with zero carry-in; emit chunk-end
// partial state (carry) and chunk decay product (Achunk). R11-identical.
__global__ void __launch_bounds__(256)
k_scanA(const float* __restrict__ hidden,
        const float* __restrict__ p_sorted,
        const int* __restrict__ rowstart,
        float* __restrict__ carry,     // [B][NCC][D]
        float* __restrict__ Achunk) {  // [B][NCC]
  const int c = blockIdx.x, b = blockIdx.y;
  const int tid = threadIdx.x;
  if (rowstart[b * (M_ + 1) + c * CHUNK_] >= L_) return;  // inactive chunk
  __shared__ float4 s_scal[CHUNK_];
  chunk_scal(p_sorted, b, c, tid, s_scal);
  __syncthreads();
  if (tid == 0) {
    float cp = 1.0f;
#pragma unroll
    for (int m = 0; m < CHUNK_; ++m) cp *= s_scal[m].x;
    Achunk[b * NCC_ + c] = cp;
  }
  const int d4 = tid * 4;
  const float* __restrict__ hp =
      hidden + ((size_t)(b * M_ + c * CHUNK_)) * D_ + d4;
  float hx = 0.f, hy = 0.f, hz = 0.f, hw = 0.f;
#pragma unroll
  for (int m = 0; m < CHUNK_; ++m) {
    const float4 s = s_scal[m];                 // a, c=dt*p, 1/dt
    const float4 x = *(const float4*)(hp + (size_t)m * D_);
    hx = fmaf(s.x, hx, s.y * bf16rf(x.x * s.z));
    hy = fmaf(s.x, hy, s.y * bf16rf(x.y * s.z));
    hz = fmaf(s.x, hz, s.y * bf16rf(x.z * s.z));
    hw = fmaf(s.x, hw, s.y * bf16rf(x.w * s.z));
  }
  *(float4*)(carry + ((size_t)(b * NCC_ + c)) * D_ + d4) =
      make_float4(hx, hy, hz, hw);
}

// Pass B: in-place inclusive scan across chunks (batch-16 loads: one
// latency per 16 chunks). 4096 independent (b,d) chains. R11-identical.
__global__ void __launch_bounds__(64)
k_scanB(float* __restrict__ carry, const float* __restrict__ Achunk) {
  const int chain = blockIdx.x * 64 + threadIdx.x;  // 0..4095
  const int bb = chain >> 10, dd = chain & 1023;
  const float* __restrict__ Ab = Achunk + bb * NCC_;
  float S = 0.0f;
  for (int g = 0; g < NCC_ / 16; ++g) {
    float v[16], A[16];
#pragma unroll
    for (int j = 0; j < 16; ++j)
      v[j] = carry[((size_t)(bb * NCC_ + g * 16 + j)) * D_ + dd];
#pragma unroll
    for (int j = 0; j < 16; ++j) A[j] = Ab[g * 16 + j];
#pragma unroll
    for (int j = 0; j < 16; ++j) { S = fmaf(A[j], S, v[j]); v[j] = S; }
#pragma unroll
    for (int j = 0; j < 16; ++j)
      carry[((size_t)(bb * NCC_ + g * 16 + j)) * D_ + dd] = v[j];
  }
}

// Pass C: inactive-exit FIRST (scalar load), then early carry-in load
// (overlaps the LDS/scal phase), local rescan of hidden with true carry-in,
// fused token scatter with nontemporal stores.
__global__ void __launch_bounds__(256)
k_scanC(const float* __restrict__ hidden,
        const float* __restrict__ p_sorted,
        const int* __restrict__ rowstart,
        const float* __restrict__ carry,
        float* __restrict__ out) {
  const int c = blockIdx.x, b = blockIdx.y;
  const int tid = threadIdx.x;
  if (rowstart[b * (M_ + 1) + c * CHUNK_] >= L_) return;  // inactive chunk
  const int d4 = tid * 4;
  __shared__ float4 s_scal[CHUNK_];
  __shared__ int    s_rs[CHUNK_ + 1];

  // issue carry-in load first so it overlaps the LDS/scal phase
  float hx = 0.f, hy = 0.f, hz = 0.f, hw = 0.f;
  if (c > 0) {
    const float4 ci =
        *(const float4*)(carry + ((size_t)(b * NCC_ + c - 1)) * D_ + d4);
    hx = ci.x; hy = ci.y; hz = ci.z; hw = ci.w;
  }
  chunk_scal(p_sorted, b, c, tid, s_scal);
  if (tid <= CHUNK_) s_rs[tid] = rowstart[b * (M_ + 1) + c * CHUNK_ + tid];
  __syncthreads();

  const float* __restrict__ hp =
      hidden + ((size_t)(b * M_ + c * CHUNK_)) * D_ + d4;
#pragma unroll
  for (int m = 0; m < CHUNK_; ++m) {
    const float4 s = s_scal[m];
    const float4 x = *(const float4*)(hp + (size_t)m * D_);
    hx = fmaf(s.x, hx, s.y * bf16rf(x.x * s.z));
    hy = fmaf(s.x, hy, s.y * bf16rf(x.y * s.z));
    hz = fmaf(s.x, hz, s.y * bf16rf(x.z * s.z));
    hw = fmaf(s.x, hw, s.y * bf16rf(x.w * s.z));
    const int r0 = s_rs[m], r1 = s_rs[m + 1];
    if (r1 > r0) {
      f32x4 o;
      o.x = bf16rf(hx); o.y = bf16rf(hy);
      o.z = bf16rf(hz); o.w = bf16rf(hw);
      for (int l = r0; l < r1; ++l)
        __builtin_nontemporal_store(
            o, (f32x4*)(out + ((size_t)(b * L_ + l)) * D_ + d4));
    }
  }
}

extern "C" void kernel_launch(void* const* d_in, const int* in_sizes, int n_in,
                              void* d_out, int out_size, void* d_ws, size_t ws_size,
                              hipStream_t stream) {
  const float* hidden = (const float*)d_in[0];
  const float* bprob  = (const float*)d_in[1];
  const void*  bmask  = d_in[2];
  float* out = (float*)d_out;

  float* p_sorted = (float*)d_ws;                            // B*M
  float* carry    = p_sorted + B_ * M_;                      // B*NCC*D
  float* Achunk   = carry + (size_t)B_ * NCC_ * D_;          // B*NCC
  int*   rowstart = (int*)(Achunk + B_ * NCC_);              // B*(M+1)

  k_prep<<<dim3(B_), dim3(1024), 0, stream>>>(bprob, bmask, p_sorted, rowstart);
  k_scanA<<<dim3(NCC_, B_), dim3(256), 0, stream>>>(hidden, p_sorted, rowstart,
                                                    carry, Achunk);
  k_scanB<<<dim3(64), dim3(64), 0, stream>>>(carry, Achunk);
  k_scanC<<<dim3(NCC_, B_), dim3(256), 0, stream>>>(hidden, p_sorted, rowstart,
                                                    carry, out);
}

// Round 15
// 66.688 us; speedup vs baseline: 1.2978x; 1.0050x over previous
//
#include <hip/hip_runtime.h>
#include <hip/hip_bf16.h>
#include <math.h>

// Problem constants (fixed by setup_inputs)
#define B_ 4
#define L_ 8192
#define M_ 4096
#define D_ 1024
#define CHUNK_ 32
#define NCC_ 128        // M_/CHUNK_
#define EPS_ 1e-4f

// clang native vector type for nontemporal builtins (same layout as float4)
typedef float f32x4 __attribute__((ext_vector_type(4)));

// Round-to-nearest-even f32 -> bf16 -> f32 (values are finite here)
__device__ __forceinline__ float bf16rf(float x) {
  unsigned u = __float_as_uint(x);
  u += 0x7FFFu + ((u >> 16) & 1u);
  u &= 0xFFFF0000u;
  return __uint_as_float(u);
}

// boundary_mask may arrive as bool8 (fmt 0), int32 (fmt 1), or float32 (fmt 2)
__device__ __forceinline__ bool mask_at(const void* mb, int fmt, int i) {
  if (fmt == 0) return ((const unsigned char*)mb)[i] != 0;
  if (fmt == 1) return ((const int*)mb)[i] != 0;
  return ((const float*)mb)[i] != 0.0f;
}

// Compute per-chunk scalars into LDS: s_scal[tid] = (a, c=dt*p, 1/dt, 0)
// for tid < CHUNK_. Deterministic -> identical values in scanA and scanC.
__device__ __forceinline__ void chunk_scal(const float* __restrict__ p_sorted,
                                           int b, int c, int tid,
                                           float4* s_scal) {
  if (tid < CHUNK_) {
    float p = p_sorted[b * M_ + c * CHUNK_ + tid];
    p = fminf(fmaxf(p, EPS_), 1.0f - EPS_);
    float dtf = bf16rf(logf(1.0f / (1.0f - p)));
    s_scal[tid] = make_float4(expf(-dtf), dtf * p, 1.0f / dtf, 0.0f);
  }
}

// prep: one 1024-thread block per batch; sort-only, LDS-staged scatter,
// coalesced global write-out (R14-proven).
__global__ void __launch_bounds__(1024)
k_prep(const float* __restrict__ bprob,
       const void* __restrict__ bmask,
       float* __restrict__ p_sorted,
       int* __restrict__ rowstart) {
  const int b = blockIdx.x;
  const int tid = threadIdx.x;  // 0..1023
  const int lane = tid & 63, wid = tid >> 6;
  __shared__ int s_flags[2];
  __shared__ int s_wsum[17];
  __shared__ float s_p[M_];        // 16 KB
  __shared__ int   s_rsl[M_ + 1];  // 16 KB + 4

  if (tid < 2) s_flags[tid] = 0;
  __syncthreads();
  {
    const unsigned* mw = (const unsigned*)bmask;
    unsigned f0 = 0, f1 = 0;
    for (int i = tid; i < 8192; i += 1024) {
      unsigned v = mw[i];
      f0 |= v & 0xFFu;    // byte0: nonzero for u8 and i32, zero for f32
      f1 |= v & 0xFF00u;  // byte1: nonzero only for u8 (45% density)
    }
    if (f1) s_flags[0] = 1;
    if (f0) s_flags[1] = 1;
  }
  __syncthreads();
  const int fmt = s_flags[0] ? 0 : (s_flags[1] ? 1 : 2);

  // 8 contiguous tokens per thread
  const int base_l = tid * (L_ / 1024);
  bool mloc[L_ / 1024];
  int cnt = 0;
#pragma unroll
  for (int j = 0; j < L_ / 1024; ++j) {
    mloc[j] = mask_at(bmask, fmt, b * L_ + base_l + j);
    cnt += mloc[j] ? 1 : 0;
  }
  // wave-level inclusive scan of cnt (wave = 64 on gfx950)
  int incl = cnt;
#pragma unroll
  for (int off = 1; off < 64; off <<= 1) {
    int t = __shfl_up(incl, off);
    if (lane >= off) incl += t;
  }
  if (lane == 63) s_wsum[wid] = incl;
  // default rowstart while the scan settles
  for (int r = tid; r <= M_; r += 1024) s_rsl[r] = L_;
  __syncthreads();
  if (tid == 0) {
    int acc = 0;
#pragma unroll
    for (int w = 0; w < 16; ++w) { int t = s_wsum[w]; s_wsum[w] = acc; acc += t; }
    s_wsum[16] = acc;
  }
  __syncthreads();
  const int excl = s_wsum[wid] + incl - cnt;
  const int nb = s_wsum[16];

  int run = excl;
#pragma unroll
  for (int j = 0; j < L_ / 1024; ++j) {
    int l = base_l + j;
    bool mb = mloc[j];
    int pos = mb ? run : (nb + (l - run));
    run += mb ? 1 : 0;
    if (pos < M_) {
      s_p[pos] = bprob[((size_t)(b * L_ + l)) * 2 + 1];
      if (mb) s_rsl[pos] = l;
    }
  }
  __syncthreads();

  // coalesced write-out
  for (int m = tid; m < M_; m += 1024) p_sorted[b * M_ + m] = s_p[m];
  for (int r = tid; r <= M_; r += 1024) rowstart[b * (M_ + 1) + r] = s_rsl[r];
}

// Pass A: per-(batch,chunk) local scan with zero carry-in; emit chunk-end
// partial state (carry) and chunk decay product (Achunk). Regular loads
// (warm L3 for scanC's re-read).
__global__ void __launch_bounds__(256)
k_scanA(const float* __restrict__ hidden,
        const float* __restrict__ p_sorted,
        const int* __restrict__ rowstart,
        float* __restrict__ carry,     // [B][NCC][D]
        float* __restrict__ Achunk) {  // [B][NCC]
  const int c = blockIdx.x, b = blockIdx.y;
  const int tid = threadIdx.x;
  if (rowstart[b * (M_ + 1) + c * CHUNK_] >= L_) return;  // inactive chunk
  __shared__ float4 s_scal[CHUNK_];
  chunk_scal(p_sorted, b, c, tid, s_scal);
  __syncthreads();
  if (tid == 0) {
    float cp = 1.0f;
#pragma unroll
    for (int m = 0; m < CHUNK_; ++m) cp *= s_scal[m].x;
    Achunk[b * NCC_ + c] = cp;
  }
  const int d4 = tid * 4;
  const float* __restrict__ hp =
      hidden + ((size_t)(b * M_ + c * CHUNK_)) * D_ + d4;
  float hx = 0.f, hy = 0.f, hz = 0.f, hw = 0.f;
#pragma unroll
  for (int m = 0; m < CHUNK_; ++m) {
    const float4 s = s_scal[m];                 // a, c=dt*p, 1/dt
    const float4 x = *(const float4*)(hp + (size_t)m * D_);
    hx = fmaf(s.x, hx, s.y * bf16rf(x.x * s.z));
    hy = fmaf(s.x, hy, s.y * bf16rf(x.y * s.z));
    hz = fmaf(s.x, hz, s.y * bf16rf(x.z * s.z));
    hw = fmaf(s.x, hw, s.y * bf16rf(x.w * s.z));
  }
  *(float4*)(carry + ((size_t)(b * NCC_ + c)) * D_ + d4) =
      make_float4(hx, hy, hz, hw);
}

// Pass B: in-place inclusive scan across chunks (batch-16 loads: one
// latency per 16 chunks). 4096 independent (b,d) chains.
__global__ void __launch_bounds__(64)
k_scanB(float* __restrict__ carry, const float* __restrict__ Achunk) {
  const int chain = blockIdx.x * 64 + threadIdx.x;  // 0..4095
  const int bb = chain >> 10, dd = chain & 1023;
  const float* __restrict__ Ab = Achunk + bb * NCC_;
  float S = 0.0f;
  for (int g = 0; g < NCC_ / 16; ++g) {
    float v[16], A[16];
#pragma unroll
    for (int j = 0; j < 16; ++j)
      v[j] = carry[((size_t)(bb * NCC_ + g * 16 + j)) * D_ + dd];
#pragma unroll
    for (int j = 0; j < 16; ++j) A[j] = Ab[g * 16 + j];
#pragma unroll
    for (int j = 0; j < 16; ++j) { S = fmaf(A[j], S, v[j]); v[j] = S; }
#pragma unroll
    for (int j = 0; j < 16; ++j)
      carry[((size_t)(bb * NCC_ + g * 16 + j)) * D_ + dd] = v[j];
  }
}

// Pass C: inactive-exit first, early carry-in load, local rescan of hidden
// (nontemporal loads: read-once, keep L2 free for the store stream), fused
// token scatter with nontemporal stores.
__global__ void __launch_bounds__(256)
k_scanC(const float* __restrict__ hidden,
        const float* __restrict__ p_sorted,
        const int* __restrict__ rowstart,
        const float* __restrict__ carry,
        float* __restrict__ out) {
  const int c = blockIdx.x, b = blockIdx.y;
  const int tid = threadIdx.x;
  if (rowstart[b * (M_ + 1) + c * CHUNK_] >= L_) return;  // inactive chunk
  const int d4 = tid * 4;
  __shared__ float4 s_scal[CHUNK_];
  __shared__ int    s_rs[CHUNK_ + 1];

  // issue carry-in load first so it overlaps the LDS/scal phase
  float hx = 0.f, hy = 0.f, hz = 0.f, hw = 0.f;
  if (c > 0) {
    const f32x4 ci = __builtin_nontemporal_load(
        (const f32x4*)(carry + ((size_t)(b * NCC_ + c - 1)) * D_ + d4));
    hx = ci.x; hy = ci.y; hz = ci.z; hw = ci.w;
  }
  chunk_scal(p_sorted, b, c, tid, s_scal);
  if (tid <= CHUNK_) s_rs[tid] = rowstart[b * (M_ + 1) + c * CHUNK_ + tid];
  __syncthreads();

  const float* __restrict__ hp =
      hidden + ((size_t)(b * M_ + c * CHUNK_)) * D_ + d4;
#pragma unroll
  for (int m = 0; m < CHUNK_; ++m) {
    const float4 s = s_scal[m];
    const f32x4 x =
        __builtin_nontemporal_load((const f32x4*)(hp + (size_t)m * D_));
    hx = fmaf(s.x, hx, s.y * bf16rf(x.x * s.z));
    hy = fmaf(s.x, hy, s.y * bf16rf(x.y * s.z));
    hz = fmaf(s.x, hz, s.y * bf16rf(x.z * s.z));
    hw = fmaf(s.x, hw, s.y * bf16rf(x.w * s.z));
    const int r0 = s_rs[m], r1 = s_rs[m + 1];
    if (r1 > r0) {
      f32x4 o;
      o.x = bf16rf(hx); o.y = bf16rf(hy);
      o.z = bf16rf(hz); o.w = bf16rf(hw);
      for (int l = r0; l < r1; ++l)
        __builtin_nontemporal_store(
            o, (f32x4*)(out + ((size_t)(b * L_ + l)) * D_ + d4));
    }
  }
}

extern "C" void kernel_launch(void* const* d_in, const int* in_sizes, int n_in,
                              void* d_out, int out_size, void* d_ws, size_t ws_size,
                              hipStream_t stream) {
  const float* hidden = (const float*)d_in[0];
  const float* bprob  = (const float*)d_in[1];
  const void*  bmask  = d_in[2];
  float* out = (float*)d_out;

  float* p_sorted = (float*)d_ws;                            // B*M
  float* carry    = p_sorted + B_ * M_;                      // B*NCC*D
  float* Achunk   = carry + (size_t)B_ * NCC_ * D_;          // B*NCC
  int*   rowstart = (int*)(Achunk + B_ * NCC_);              // B*(M+1)

  k_prep<<<dim3(B_), dim3(1024), 0, stream>>>(bprob, bmask, p_sorted, rowstart);
  k_scanA<<<dim3(NCC_, B_), dim3(256), 0, stream>>>(hidden, p_sorted, rowstart,
                                                    carry, Achunk);
  k_scanB<<<dim3(64), dim3(64), 0, stream>>>(carry, Achunk);
  k_scanC<<<dim3(NCC_, B_), dim3(256), 0, stream>>>(hidden, p_sorted, rowstart,
                                                    carry, out);
}